// Round 4
// baseline (29.871 us; speedup 1.0000x reference)
//
#include <hip/hip_runtime.h>
#include <hip/hip_bf16.h>

typedef __attribute__((ext_vector_type(8))) short bf16x8;   // MFMA A/B frag (8 bf16)
typedef __attribute__((ext_vector_type(4))) float f32x4;    // MFMA C/D frag

constexpr int BM = 64;      // output rows (h) per block
constexpr int BN = 64;      // output cols (w) per block
constexpr int BK = 64;      // points per K-step
constexpr int NPTS = 4096;
constexpr int HH = 256;
constexpr int WW = 256;
constexpr int NBANDS = 4;   // 64-wide x tile-columns
constexpr int CAPB = 2048;  // per-band list capacity (mean ~1300, sd ~30)
constexpr int CAP  = 2048;  // per-tile compacted capacity (mean ~415)

// S = sqrt(INV_VAR * log2(e)); exp(-INV_VAR*d^2) = exp2(-(S*d)^2)
#define SCALE_S 0.56621453f
// cutoff: dropped-point contribution <= 1e5*exp(-0.2222*100) = 2.2e-5 each
#define DCUT 10.0f

__device__ inline short f2bs(float x) {
    __hip_bfloat16 b = __float2bfloat16(x);   // RNE
    return __builtin_bit_cast(short, b);
}

// ---------------- Kernel A: deterministic per-(bk, x-band) binning ----------
__global__ __launch_bounds__(256, 2) void bin_kernel(
    const float* __restrict__ p2d,   // (32, 4096, 2)
    const float* __restrict__ pz,    // (32, 4096)
    int*   __restrict__ cnt,         // [32*4]
    float* __restrict__ bxs,         // [32*4][CAPB]  x*S
    float* __restrict__ bys,         // [32*4][CAPB]  y*S
    float* __restrict__ bzi)         // [32*4][CAPB]  1/max(z,1e-5)
{
    const int band = blockIdx.x;     // 0..3
    const int bk   = blockIdx.y;     // 0..31
    const int tid  = threadIdx.x;
    const int wid  = tid >> 6;
    const int lane = tid & 63;
    __shared__ int scnt[4];

    const size_t pbase = (size_t)bk * NPTS;
    const float2* __restrict__ pxy = reinterpret_cast<const float2*>(p2d) + pbase;
    const float xlo = 64.f * band - DCUT;          // matches R1 tile x-window
    const float xhi = 64.f * band + 63.f + DCUT;

    // pass 1: per-wave counts (wave w owns k in [w*1024, w*1024+1024))
    int mycnt = 0;
    #pragma unroll 4
    for (int it = 0; it < 16; ++it) {
        const int k = (wid << 10) + (it << 6) + lane;
        float2 xy = pxy[k];
        bool in = (xy.x > xlo) && (xy.x < xhi);
        mycnt += __popcll(__ballot(in));
    }
    if (lane == 0) scnt[wid] = mycnt;
    __syncthreads();

    int base = 0;
    #pragma unroll
    for (int w = 0; w < 4; ++w) base += (w < wid) ? scnt[w] : 0;
    const int total = scnt[0] + scnt[1] + scnt[2] + scnt[3];
    const int slot  = bk * NBANDS + band;
    if (tid == 0) cnt[slot] = (total < CAPB) ? total : CAPB;

    float* __restrict__ oxs = bxs + (size_t)slot * CAPB;
    float* __restrict__ oys = bys + (size_t)slot * CAPB;
    float* __restrict__ ozi = bzi + (size_t)slot * CAPB;

    // pass 2: ordered write, pre-scaled SoA
    #pragma unroll 4
    for (int it = 0; it < 16; ++it) {
        const int k = (wid << 10) + (it << 6) + lane;
        float2 xy = pxy[k];
        bool in = (xy.x > xlo) && (xy.x < xhi);
        unsigned long long b = __ballot(in);
        int pos = __popcll(b & ((1ull << lane) - 1ull));
        const int o = base + pos;
        if (in && o < CAPB) {
            oxs[o] = xy.x * SCALE_S;
            oys[o] = xy.y * SCALE_S;
            ozi[o] = __builtin_amdgcn_rcpf(fmaxf(pz[pbase + k], 1e-5f));
        }
        base += __popcll(b);
    }
}

// ---------------- Kernel B: per-tile raster (R1 structure, band-fed) --------
__global__ __launch_bounds__(256, 2) void soft_raster_kernel(
    const int*   __restrict__ cnt,
    const float* __restrict__ bxs,
    const float* __restrict__ bys,
    const float* __restrict__ bzi,
    float* __restrict__ out)         // (32, 256, 256)
{
    const int bk  = blockIdx.z;
    const int tm  = blockIdx.y * BM;
    const int tn  = blockIdx.x * BN;
    const int tid = threadIdx.x;

    __shared__ __align__(16) unsigned short lwy[BM * BK];  // [m][k], XOR-swizzled
    __shared__ __align__(16) unsigned short lwx[BN * BK];  // [n][k], XOR-swizzled
    __shared__ unsigned short lidx[CAP];                   // band-local indices
    __shared__ int scnt[4];
    __shared__ float lys[BK];   // y * S
    __shared__ float lxs[BK];   // x * S
    __shared__ float lzi[BK];   // 1/max(z,1e-5), 0 for tail padding

    const int wid  = tid >> 6;          // wave 0..3 -> 2x2
    const int lane = tid & 63;
    const int wm   = (wid >> 1) << 5;   // wave row offset (0/32)
    const int wn   = (wid & 1) << 5;    // wave col offset (0/32)
    const int g    = lane >> 4;         // k-group 0..3
    const int r    = lane & 15;

    const int slot = bk * NBANDS + blockIdx.x;
    int n = cnt[slot];
    n = (n < CAPB) ? n : CAPB;
    const float* __restrict__ xs_ = bxs + (size_t)slot * CAPB;
    const float* __restrict__ ys_ = bys + (size_t)slot * CAPB;
    const float* __restrict__ zi_ = bzi + (size_t)slot * CAPB;

    // y-window in pre-scaled space (S > 0, monotonic)
    const float ylo_s = ((float)tm - DCUT) * SCALE_S;
    const float yhi_s = ((float)(tm + BM - 1) + DCUT) * SCALE_S;

    // ---- deterministic ordered y-filter over the band list ----
    // wave w owns [w*Q, min((w+1)*Q, n)), Q multiple of 64
    const int Q    = ((n + 255) >> 8) << 6;
    const int jbeg = wid * Q;
    const int jend = ((jbeg + Q) < n) ? (jbeg + Q) : n;

    int mycnt = 0;
    for (int j0 = jbeg; j0 < jend; j0 += 64) {
        const int j = j0 + lane;
        bool in = false;
        if (j < jend) {
            float ys = ys_[j];
            in = (ys > ylo_s) && (ys < yhi_s);
        }
        mycnt += __popcll(__ballot(in));
    }
    if (lane == 0) scnt[wid] = mycnt;
    __syncthreads();

    int base = 0;
    #pragma unroll
    for (int w = 0; w < 4; ++w) base += (w < wid) ? scnt[w] : 0;
    int total = scnt[0] + scnt[1] + scnt[2] + scnt[3];
    total = (total < CAP) ? total : CAP;

    for (int j0 = jbeg; j0 < jend; j0 += 64) {
        const int j = j0 + lane;
        bool in = false;
        if (j < jend) {
            float ys = ys_[j];
            in = (ys > ylo_s) && (ys < yhi_s);
        }
        unsigned long long b = __ballot(in);
        int pos = __popcll(b & ((1ull << lane) - 1ull));
        if (in && (base + pos) < CAP) lidx[base + pos] = (unsigned short)j;
        base += __popcll(b);
    }
    __syncthreads();

    f32x4 acc[2][2] = {};

    for (int k0 = 0; k0 < total; k0 += BK) {
        __syncthreads();   // protect LDS point arrays from previous readers

        // ---- gather up to 64 compacted points (already scaled) ----
        if (tid < BK) {
            const int j = k0 + tid;
            float xs = 0.f, ys = 0.f, zi = 0.f;   // tail: weight-0 points
            if (j < total) {
                const int kk = lidx[j];
                xs = xs_[kk]; ys = ys_[kk]; zi = zi_[kk];
            }
            lxs[tid] = xs; lys[tid] = ys; lzi[tid] = zi;
        }
        __syncthreads();

        // ---- generate Wy (64x64) and Wx (64x64) bf16 tiles into LDS ----
        #pragma unroll
        for (int half = 0; half < 2; ++half) {
            const float* coord      = (half == 0) ? lys : lxs;
            unsigned short* dst     = (half == 0) ? lwy : lwx;
            const int       cb      = (half == 0) ? tm  : tn;
            #pragma unroll
            for (int it = 0; it < 2; ++it) {
                const int cc = tid + (it << 8);       // 0..511
                const int q  = cc >> 3;               // coordinate within tile
                const int kg = cc & 7;                // k-group (8 points)
                const float qs = (float)(cb + q) * SCALE_S;
                float4 c0 = *reinterpret_cast<const float4*>(&coord[kg * 8]);
                float4 c1 = *reinterpret_cast<const float4*>(&coord[kg * 8 + 4]);
                float e0 = exp2f(-((qs - c0.x) * (qs - c0.x)));
                float e1 = exp2f(-((qs - c0.y) * (qs - c0.y)));
                float e2 = exp2f(-((qs - c0.z) * (qs - c0.z)));
                float e3 = exp2f(-((qs - c0.w) * (qs - c0.w)));
                float e4 = exp2f(-((qs - c1.x) * (qs - c1.x)));
                float e5 = exp2f(-((qs - c1.y) * (qs - c1.y)));
                float e6 = exp2f(-((qs - c1.z) * (qs - c1.z)));
                float e7 = exp2f(-((qs - c1.w) * (qs - c1.w)));
                if (half == 0) {   // fold inv_z into Wy
                    float4 z0 = *reinterpret_cast<const float4*>(&lzi[kg * 8]);
                    float4 z1 = *reinterpret_cast<const float4*>(&lzi[kg * 8 + 4]);
                    e0 *= z0.x; e1 *= z0.y; e2 *= z0.z; e3 *= z0.w;
                    e4 *= z1.x; e5 *= z1.y; e6 *= z1.z; e7 *= z1.w;
                }
                bf16x8 v;
                v[0] = f2bs(e0); v[1] = f2bs(e1); v[2] = f2bs(e2); v[3] = f2bs(e3);
                v[4] = f2bs(e4); v[5] = f2bs(e5); v[6] = f2bs(e6); v[7] = f2bs(e7);
                const int idx = ((q << 6) + (kg << 3)) ^ ((q & 7) << 3);  // swizzle
                *reinterpret_cast<bf16x8*>(&dst[idx]) = v;
            }
        }
        __syncthreads();

        // ---- MFMA: 2 K-substeps of 32, per-wave 2x2 fragments of 16x16 ----
        #pragma unroll
        for (int kk = 0; kk < 2; ++kk) {
            bf16x8 af[2], bfr[2];
            #pragma unroll
            for (int i = 0; i < 2; ++i) {
                const int qa = wm + (i << 4) + r;
                af[i] = *reinterpret_cast<const bf16x8*>(
                    &lwy[((qa << 6) + (kk << 5) + (g << 3)) ^ ((qa & 7) << 3)]);
                const int qb = wn + (i << 4) + r;
                bfr[i] = *reinterpret_cast<const bf16x8*>(
                    &lwx[((qb << 6) + (kk << 5) + (g << 3)) ^ ((qb & 7) << 3)]);
            }
            #pragma unroll
            for (int mi = 0; mi < 2; ++mi)
                #pragma unroll
                for (int ni = 0; ni < 2; ++ni)
                    acc[mi][ni] = __builtin_amdgcn_mfma_f32_16x16x32_bf16(
                        af[mi], bfr[ni], acc[mi][ni], 0, 0, 0);
        }
    }

    // ---- epilogue: C/D layout col=lane&15, row=4*(lane>>4)+reg ----
    float* obase = out + (size_t)bk * (HH * WW);
    #pragma unroll
    for (int mi = 0; mi < 2; ++mi) {
        #pragma unroll
        for (int ni = 0; ni < 2; ++ni) {
            const int col  = tn + wn + (ni << 4) + r;
            const int row0 = tm + wm + (mi << 4) + (g << 2);
            #pragma unroll
            for (int j = 0; j < 4; ++j)
                obase[(size_t)(row0 + j) * WW + col] = acc[mi][ni][j];
        }
    }
}

extern "C" void kernel_launch(void* const* d_in, const int* in_sizes, int n_in,
                              void* d_out, int out_size, void* d_ws, size_t ws_size,
                              hipStream_t stream) {
    const float* p2d = (const float*)d_in[0];
    const float* pz  = (const float*)d_in[1];
    float* out       = (float*)d_out;
    const int nbk    = in_sizes[1] / NPTS;   // B*K = 32
    const int nslots = nbk * NBANDS;         // 128

    int*   cnt = (int*)d_ws;
    float* bxs = (float*)((char*)d_ws + 1024);
    float* bys = bxs + (size_t)nslots * CAPB;
    float* bzi = bys + (size_t)nslots * CAPB;

    hipLaunchKernelGGL(bin_kernel, dim3(NBANDS, nbk), dim3(256), 0, stream,
                       p2d, pz, cnt, bxs, bys, bzi);
    hipLaunchKernelGGL(soft_raster_kernel, dim3(WW / BN, HH / BM, nbk),
                       dim3(256), 0, stream, cnt, bxs, bys, bzi, out);
}

// Round 5
// 23.906 us; speedup vs baseline: 1.2495x; 1.2495x over previous
//
#include <hip/hip_runtime.h>
#include <hip/hip_bf16.h>

typedef __attribute__((ext_vector_type(8))) short bf16x8;   // MFMA A/B frag (8 bf16)
typedef __attribute__((ext_vector_type(4))) float f32x4;    // MFMA C/D frag

constexpr int BM = 32;      // output rows (h) per block
constexpr int BN = 32;      // output cols (w) per block
constexpr int BK = 32;      // points per K-step
constexpr int NPTS = 4096;
constexpr int HH = 256;
constexpr int WW = 256;
constexpr int CAP = 512;    // max compacted points per tile (mean ~159, sd ~12)

// S = sqrt(INV_VAR * log2(e)); exp(-INV_VAR*d^2) = exp2(-(S*d)^2)
#define SCALE_S 0.56621453f
// cutoff: dropped-point contribution <= 1e5*exp(-0.2222*100) = 2.2e-5 each
#define DCUT 10.0f

__device__ inline short f2bs(float x) {
    __hip_bfloat16 b = __float2bfloat16(x);   // RNE
    return __builtin_bit_cast(short, b);
}

// 4 waves/block, each wave owns one 16x16 output quadrant.
// 2048 blocks -> 8 blocks/CU -> 32 waves/CU (full wave occupancy).
__global__ __launch_bounds__(256, 8) void soft_raster_kernel(
    const float* __restrict__ p2d,   // (32, 4096, 2)
    const float* __restrict__ pz,    // (32, 4096)
    float* __restrict__ out)         // (32, 256, 256)
{
    const int bk  = blockIdx.z;
    const int tm  = blockIdx.y * BM;
    const int tn  = blockIdx.x * BN;
    const int tid = threadIdx.x;

    __shared__ __align__(16) unsigned short lwy[BM * BK];  // [m][k]
    __shared__ __align__(16) unsigned short lwx[BN * BK];  // [n][k]
    __shared__ unsigned short lidx[CAP];                   // compacted point ids
    __shared__ int scnt[4];
    __shared__ float lys[BK];   // y * S
    __shared__ float lxs[BK];   // x * S
    __shared__ float lzi[BK];   // 1/max(z,1e-5), 0 for tail padding

    const int wid  = tid >> 6;          // wave 0..3 -> 2x2 quadrants
    const int lane = tid & 63;
    const int wm   = (wid >> 1) << 4;   // wave row offset (0/16)
    const int wn   = (wid & 1) << 4;    // wave col offset (0/16)
    const int g    = lane >> 4;         // k-group 0..3
    const int r    = lane & 15;

    const size_t pbase = (size_t)bk * NPTS;
    const float2* __restrict__ pxy = reinterpret_cast<const float2*>(p2d) + pbase;

    // ---- deterministic ordered compaction of in-window points (R1 scheme) ----
    const float xlo = (float)tn - DCUT, xhi = (float)(tn + BN - 1) + DCUT;
    const float ylo = (float)tm - DCUT, yhi = (float)(tm + BM - 1) + DCUT;

    // pass A: per-wave counts (wave w owns k in [w*1024, (w+1)*1024))
    int mycnt = 0;
    #pragma unroll 4
    for (int it = 0; it < 16; ++it) {
        const int k = (wid << 10) + (it << 6) + lane;
        float2 xy = pxy[k];
        bool in = (xy.x > xlo) && (xy.x < xhi) && (xy.y > ylo) && (xy.y < yhi);
        mycnt += __popcll(__ballot(in));
    }
    if (lane == 0) scnt[wid] = mycnt;
    __syncthreads();

    int base = 0;
    #pragma unroll
    for (int w = 0; w < 4; ++w) base += (w < wid) ? scnt[w] : 0;
    int total = scnt[0] + scnt[1] + scnt[2] + scnt[3];
    total = (total < CAP) ? total : CAP;

    // pass B: ordered write of compacted indices
    #pragma unroll 4
    for (int it = 0; it < 16; ++it) {
        const int k = (wid << 10) + (it << 6) + lane;
        float2 xy = pxy[k];
        bool in = (xy.x > xlo) && (xy.x < xhi) && (xy.y > ylo) && (xy.y < yhi);
        unsigned long long b = __ballot(in);
        int pos = __popcll(b & ((1ull << lane) - 1ull));
        if (in && (base + pos) < CAP) lidx[base + pos] = (unsigned short)k;
        base += __popcll(b);
    }
    __syncthreads();

    f32x4 acc = {};   // single 16x16 quadrant per wave

    for (int k0 = 0; k0 < total; k0 += BK) {
        __syncthreads();   // protect LDS from previous iteration's readers

        // ---- gather up to 32 compacted points into LDS (pre-scaled) ----
        if (tid < BK) {
            const int j = k0 + tid;
            float xs = 0.f, ys = 0.f, zi = 0.f;   // tail: weight-0 points
            if (j < total) {
                const int kk = lidx[j];
                float2 xy = pxy[kk];
                float  z  = pz[pbase + kk];
                xs = xy.x * SCALE_S;
                ys = xy.y * SCALE_S;
                zi = __builtin_amdgcn_rcpf(fmaxf(z, 1e-5f));
            }
            lxs[tid] = xs; lys[tid] = ys; lzi[tid] = zi;
        }
        __syncthreads();

        // ---- generate Wy (32x32) and Wx (32x32): one 8-value chunk/thread ----
        {
            const bool isy = (tid < 128);          // waves 0,1: Wy; waves 2,3: Wx
            const float* coord  = isy ? lys : lxs;
            unsigned short* dst = isy ? lwy : lwx;
            const int cb        = isy ? tm  : tn;
            const int cc = tid & 127;
            const int q  = cc >> 2;                // coordinate within tile 0..31
            const int kg = cc & 3;                 // k-group (8 points)
            const float qs = (float)(cb + q) * SCALE_S;
            float4 c0 = *reinterpret_cast<const float4*>(&coord[kg * 8]);
            float4 c1 = *reinterpret_cast<const float4*>(&coord[kg * 8 + 4]);
            float e0 = exp2f(-((qs - c0.x) * (qs - c0.x)));
            float e1 = exp2f(-((qs - c0.y) * (qs - c0.y)));
            float e2 = exp2f(-((qs - c0.z) * (qs - c0.z)));
            float e3 = exp2f(-((qs - c0.w) * (qs - c0.w)));
            float e4 = exp2f(-((qs - c1.x) * (qs - c1.x)));
            float e5 = exp2f(-((qs - c1.y) * (qs - c1.y)));
            float e6 = exp2f(-((qs - c1.z) * (qs - c1.z)));
            float e7 = exp2f(-((qs - c1.w) * (qs - c1.w)));
            if (isy) {   // fold inv_z into Wy
                float4 z0 = *reinterpret_cast<const float4*>(&lzi[kg * 8]);
                float4 z1 = *reinterpret_cast<const float4*>(&lzi[kg * 8 + 4]);
                e0 *= z0.x; e1 *= z0.y; e2 *= z0.z; e3 *= z0.w;
                e4 *= z1.x; e5 *= z1.y; e6 *= z1.z; e7 *= z1.w;
            }
            bf16x8 v;
            v[0] = f2bs(e0); v[1] = f2bs(e1); v[2] = f2bs(e2); v[3] = f2bs(e3);
            v[4] = f2bs(e4); v[5] = f2bs(e5); v[6] = f2bs(e6); v[7] = f2bs(e7);
            // [q][k] layout, rows of 32 ushort; write/read patterns are
            // bank-uniform (8 words/bank per b128) -> no swizzle needed
            *reinterpret_cast<bf16x8*>(&dst[(q << 5) + (kg << 3)]) = v;
        }
        __syncthreads();

        // ---- MFMA: one 16x16x32 per wave per K-step ----
        {
            bf16x8 af = *reinterpret_cast<const bf16x8*>(
                &lwy[((wm + r) << 5) + (g << 3)]);
            bf16x8 bfr = *reinterpret_cast<const bf16x8*>(
                &lwx[((wn + r) << 5) + (g << 3)]);
            acc = __builtin_amdgcn_mfma_f32_16x16x32_bf16(af, bfr, acc, 0, 0, 0);
        }
    }

    // ---- epilogue: C/D layout col=lane&15, row=4*(lane>>4)+reg ----
    float* obase = out + (size_t)bk * (HH * WW);
    const int col  = tn + wn + r;
    const int row0 = tm + wm + (g << 2);
    #pragma unroll
    for (int j = 0; j < 4; ++j)
        obase[(size_t)(row0 + j) * WW + col] = acc[j];
}

extern "C" void kernel_launch(void* const* d_in, const int* in_sizes, int n_in,
                              void* d_out, int out_size, void* d_ws, size_t ws_size,
                              hipStream_t stream) {
    const float* p2d = (const float*)d_in[0];
    const float* pz  = (const float*)d_in[1];
    float* out       = (float*)d_out;
    const int nbk    = in_sizes[1] / NPTS;   // B*K = 32
    dim3 grid(WW / BN, HH / BM, nbk);        // (8, 8, 32) = 2048 WGs
    dim3 block(256);
    hipLaunchKernelGGL(soft_raster_kernel, grid, block, 0, stream, p2d, pz, out);
}

// Round 6
// 18.516 us; speedup vs baseline: 1.6132x; 1.2911x over previous
//
#include <hip/hip_runtime.h>
#include <hip/hip_bf16.h>

typedef __attribute__((ext_vector_type(8))) short bf16x8;   // MFMA A/B frag (8 bf16)
typedef __attribute__((ext_vector_type(4))) float f32x4;    // MFMA C/D frag
typedef __attribute__((ext_vector_type(4))) unsigned int u32x4;

constexpr int BM = 32;      // output rows (h) per block
constexpr int BN = 32;      // output cols (w) per block
constexpr int BK = 32;      // points per K-step
constexpr int NPTS = 4096;
constexpr int HH = 256;
constexpr int WW = 256;
constexpr int SEGCAP = 128; // per-wave segment capacity (mean ~40, sd ~6)

// S = sqrt(INV_VAR * log2(e)); exp(-INV_VAR*d^2) = exp2(-(S*d)^2)
#define SCALE_S 0.56621453f
// cutoff: dropped-point contribution <= 1e5*2^-32 = 2.3e-5 each
#define DCUT 10.0f

// pack two f32 -> two bf16 (round-to-nearest, ties up; positive finite inputs)
__device__ inline unsigned int pkbf(float a, float b) {
    unsigned ua = __builtin_bit_cast(unsigned, a);
    unsigned ub = __builtin_bit_cast(unsigned, b);
    return ((ua + 0x8000u) >> 16) | ((ub + 0x8000u) & 0xFFFF0000u);
}

// 4 waves/block, each wave owns one 16x16 output quadrant.
// 2048 blocks -> 8 blocks/CU -> 32 waves/CU.
__global__ __launch_bounds__(256, 8) void soft_raster_kernel(
    const float* __restrict__ p2d,   // (32, 4096, 2)
    const float* __restrict__ pz,    // (32, 4096)
    float* __restrict__ out)         // (32, 256, 256)
{
    const int bk  = blockIdx.z;
    const int tm  = blockIdx.y * BM;
    const int tn  = blockIdx.x * BN;
    const int tid = threadIdx.x;

    __shared__ __align__(16) unsigned short lwy[BM * BK];  // [m][k]
    __shared__ __align__(16) unsigned short lwx[BN * BK];  // [n][k]
    __shared__ unsigned short lidx[4 * SEGCAP];            // per-wave segments
    __shared__ int scnt[4];
    __shared__ float lys[BK];   // y * S
    __shared__ float lxs[BK];   // x * S
    __shared__ float lzi[BK];   // log2(1/max(z,1e-5)); -inf for tail padding

    const int wid  = tid >> 6;          // wave 0..3 -> 2x2 quadrants
    const int lane = tid & 63;
    const int wm   = (wid >> 1) << 4;   // wave row offset (0/16)
    const int wn   = (wid & 1) << 4;    // wave col offset (0/16)
    const int g    = lane >> 4;         // k-group 0..3
    const int r    = lane & 15;

    const size_t pbase = (size_t)bk * NPTS;
    const float2* __restrict__ pxy = reinterpret_cast<const float2*>(p2d) + pbase;

    const float xlo = (float)tn - DCUT, xhi = (float)(tn + BN - 1) + DCUT;
    const float ylo = (float)tm - DCUT, yhi = (float)(tm + BM - 1) + DCUT;

    // ---- single-pass segmented compaction ----
    // wave w owns k in [w*1024, (w+1)*1024), writes to lidx[w*SEGCAP ...]
    int base = 0;
    #pragma unroll 4
    for (int it = 0; it < 16; ++it) {
        const int k = (wid << 10) + (it << 6) + lane;
        float2 xy = pxy[k];
        bool in = (xy.x > xlo) && (xy.x < xhi) && (xy.y > ylo) && (xy.y < yhi);
        unsigned long long b = __ballot(in);
        int pos = __popcll(b & ((1ull << lane) - 1ull));
        if (in && (base + pos) < SEGCAP)
            lidx[(wid << 7) + base + pos] = (unsigned short)k;
        base += __popcll(b);     // wave-uniform
    }
    if (lane == 0) scnt[wid] = (base < SEGCAP) ? base : SEGCAP;
    __syncthreads();

    const int c0 = scnt[0], c1 = scnt[1], c2 = scnt[2], c3 = scnt[3];
    const int p1 = c0, p2 = c0 + c1, p3 = c0 + c1 + c2;
    const int total = p3 + c3;

    f32x4 acc = {};   // single 16x16 quadrant per wave

    for (int k0 = 0; k0 < total; k0 += BK) {
        __syncthreads();   // protect LDS point arrays from previous readers

        // ---- gather up to 32 compacted points into LDS (pre-scaled) ----
        if (tid < BK) {
            const int j = k0 + tid;
            float xs = 0.f, ys = 0.f, zi = -__builtin_inff();  // tail: -inf -> 0
            if (j < total) {
                const int seg = (j >= p1) + (j >= p2) + (j >= p3);
                const int off = (seg > 0) ? ((seg > 1) ? ((seg > 2) ? p3 : p2) : p1) : 0;
                const int kk  = lidx[(seg << 7) + (j - off)];
                float2 xy = pxy[kk];
                float  z  = pz[pbase + kk];
                xs = xy.x * SCALE_S;
                ys = xy.y * SCALE_S;
                zi = -__builtin_amdgcn_logf(fmaxf(z, 1e-5f));   // log2(1/z~)
            }
            lxs[tid] = xs; lys[tid] = ys; lzi[tid] = zi;
        }
        __syncthreads();

        // ---- generate Wy (32x32) and Wx (32x32): one 8-value chunk/thread ----
        {
            const bool isy = (tid < 128);          // waves 0,1: Wy; waves 2,3: Wx
            const float* coord  = isy ? lys : lxs;
            unsigned short* dst = isy ? lwy : lwx;
            const int cb        = isy ? tm  : tn;
            const int cc = tid & 127;
            const int q  = cc >> 2;                // coordinate within tile 0..31
            const int kg = cc & 3;                 // k-group (8 points)
            const float qs = (float)(cb + q) * SCALE_S;
            float4 c0v = *reinterpret_cast<const float4*>(&coord[kg * 8]);
            float4 c1v = *reinterpret_cast<const float4*>(&coord[kg * 8 + 4]);
            float m0 = 0.f, m1 = 0.f, m2 = 0.f, m3 = 0.f;
            float m4 = 0.f, m5 = 0.f, m6 = 0.f, m7 = 0.f;
            if (isy) {   // fold log2(1/z) into the exponent (wave-uniform branch)
                float4 z0 = *reinterpret_cast<const float4*>(&lzi[kg * 8]);
                float4 z1 = *reinterpret_cast<const float4*>(&lzi[kg * 8 + 4]);
                m0 = z0.x; m1 = z0.y; m2 = z0.z; m3 = z0.w;
                m4 = z1.x; m5 = z1.y; m6 = z1.z; m7 = z1.w;
            }
            const float d0 = qs - c0v.x, d1 = qs - c0v.y, d2 = qs - c0v.z, d3 = qs - c0v.w;
            const float d4 = qs - c1v.x, d5 = qs - c1v.y, d6 = qs - c1v.z, d7 = qs - c1v.w;
            const float e0 = __builtin_amdgcn_exp2f(fmaf(d0, -d0, m0));
            const float e1 = __builtin_amdgcn_exp2f(fmaf(d1, -d1, m1));
            const float e2 = __builtin_amdgcn_exp2f(fmaf(d2, -d2, m2));
            const float e3 = __builtin_amdgcn_exp2f(fmaf(d3, -d3, m3));
            const float e4 = __builtin_amdgcn_exp2f(fmaf(d4, -d4, m4));
            const float e5 = __builtin_amdgcn_exp2f(fmaf(d5, -d5, m5));
            const float e6 = __builtin_amdgcn_exp2f(fmaf(d6, -d6, m6));
            const float e7 = __builtin_amdgcn_exp2f(fmaf(d7, -d7, m7));
            u32x4 v;
            v[0] = pkbf(e0, e1); v[1] = pkbf(e2, e3);
            v[2] = pkbf(e4, e5); v[3] = pkbf(e6, e7);
            // [q][k] layout, rows of 32 ushort; b128 ops are bank-uniform
            *reinterpret_cast<u32x4*>(&dst[(q << 5) + (kg << 3)]) = v;
        }
        __syncthreads();

        // ---- MFMA: one 16x16x32 per wave per K-step ----
        {
            bf16x8 af = *reinterpret_cast<const bf16x8*>(
                &lwy[((wm + r) << 5) + (g << 3)]);
            bf16x8 bfr = *reinterpret_cast<const bf16x8*>(
                &lwx[((wn + r) << 5) + (g << 3)]);
            acc = __builtin_amdgcn_mfma_f32_16x16x32_bf16(af, bfr, acc, 0, 0, 0);
        }
    }

    // ---- epilogue: C/D layout col=lane&15, row=4*(lane>>4)+reg ----
    float* obase = out + (size_t)bk * (HH * WW);
    const int col  = tn + wn + r;
    const int row0 = tm + wm + (g << 2);
    #pragma unroll
    for (int j = 0; j < 4; ++j)
        obase[(size_t)(row0 + j) * WW + col] = acc[j];
}

extern "C" void kernel_launch(void* const* d_in, const int* in_sizes, int n_in,
                              void* d_out, int out_size, void* d_ws, size_t ws_size,
                              hipStream_t stream) {
    const float* p2d = (const float*)d_in[0];
    const float* pz  = (const float*)d_in[1];
    float* out       = (float*)d_out;
    const int nbk    = in_sizes[1] / NPTS;   // B*K = 32
    dim3 grid(WW / BN, HH / BM, nbk);        // (8, 8, 32) = 2048 WGs
    dim3 block(256);
    hipLaunchKernelGGL(soft_raster_kernel, grid, block, 0, stream, p2d, pz, out);
}